// Round 9
// baseline (347.726 us; speedup 1.0000x reference)
//
#include <hip/hip_runtime.h>
#include <hip/hip_bf16.h>

#define NPOS   100
#define BATCH  1024
#define DIN    384
#define DOUT   384
#define XROW   (NPOS * DIN)      // 38400 floats, batch-dim stride of x and out
#define WSLICE (DIN * DOUT)

#define NHALF  192               // d_out columns owned by one block
#define PBT    392               // LDS pitch (shorts): 784B rows -> bank phase 4
#define LDS_BYTES (NHALF * PBT * 2)   // 150,528 B (one block/CU)
#define NT     12                // n-tiles  (192/16)
#define NKS    12                // K-steps  (384/32)
#define NCHUNK (BATCH / 32)      // 32 chunks of 32 batch rows

typedef __attribute__((ext_vector_type(8))) short bf16x8;
typedef __attribute__((ext_vector_type(4))) float f32x4;

__device__ __forceinline__ unsigned f2bfu(float f) {
  return (unsigned)__builtin_bit_cast(unsigned short, __float2bfloat16(f));
}
__device__ __forceinline__ unsigned pack2(float a, float b) {
  return f2bfu(a) | (f2bfu(b) << 16);
}
__device__ __forceinline__ bf16x8 cvt8(float4 a, float4 b) {
  union { unsigned u[4]; bf16x8 v; } r;
  r.u[0] = pack2(a.x, a.y);
  r.u[1] = pack2(a.z, a.w);
  r.u[2] = pack2(b.x, b.y);
  r.u[3] = pack2(b.z, b.w);
  return r.v;
}

// Block = (slice, d_out half). w^T half staged to LDS ONCE; 8 waves then
// independently stream 32-row batch chunks (x -> registers -> MFMA).
// One barrier total; minimum-traffic structure: x read 2x, w 1x, out 1x.
__global__ __launch_bounds__(512, 2) void nlinear_slice(
    const float* __restrict__ x, const float* __restrict__ w,
    const float* __restrict__ bias, float* __restrict__ out)
{
  extern __shared__ short lBT[];   // [NHALF][PBT] bf16: w^T (o-major, k minor)

  const int tid  = threadIdx.x;
  const int lane = tid & 63;
  const int wv   = tid >> 6;       // 8 waves
  const int lr   = lane & 15;      // frag row/col
  const int lg   = lane >> 4;      // k-group 0..3

  const int bid   = blockIdx.x;    // 200 blocks
  const int slice = bid >> 1;
  const int half  = bid & 1;

  const float* wb = w    + (size_t)slice * WSLICE + half * NHALF;
  const float* xc = x    + (size_t)slice * DIN;
  const float* bb = bias + (size_t)slice * DOUT + half * NHALF;
  float*       ob = out  + (size_t)slice * DOUT + half * NHALF;

  // ---- one-time: stage w^T half-slice (384k x 192o) as bf16 ----
  // Coalesced float4 global reads (768B runs per k-row); scalar LDS writes
  // (one-time cost, bank behavior irrelevant).
#pragma unroll 4
  for (int i = 0; i < 36; ++i) {
    const int idx = tid + 512 * i;        // 0..18431 = 384 * 48
    const int k   = idx / 48;
    const int q   = idx - k * 48;         // o-quad
    const float4 v = *reinterpret_cast<const float4*>(wb + (size_t)k * DOUT + q * 4);
    lBT[(q * 4 + 0) * PBT + k] = (short)f2bfu(v.x);
    lBT[(q * 4 + 1) * PBT + k] = (short)f2bfu(v.y);
    lBT[(q * 4 + 2) * PBT + k] = (short)f2bfu(v.z);
    lBT[(q * 4 + 3) * PBT + k] = (short)f2bfu(v.w);
  }

  float bv[NT];
#pragma unroll
  for (int n = 0; n < NT; ++n) bv[n] = bb[n * 16 + lr];

  __syncthreads();   // the only barrier

  // ---- per-wave independent batch-chunk stream ----
#pragma unroll 1
  for (int c = wv; c < NCHUNK; c += 8) {
    const int row0 = c * 32;
    const float* xrow[2];
    xrow[0] = xc + (size_t)(row0 + lr) * XROW;
    xrow[1] = xc + (size_t)(row0 + 16 + lr) * XROW;

    f32x4 acc[2][NT];
#pragma unroll
    for (int m = 0; m < 2; ++m)
#pragma unroll
      for (int n = 0; n < NT; ++n)
        acc[m][n] = f32x4{0.f, 0.f, 0.f, 0.f};

    // A-frag loads: lane lr -> row, lg -> 32B k-group; inst-pair covers
    // 16 rows x 128B fully (one K-step per line).
    float4 xa[2][2];
#pragma unroll
    for (int m = 0; m < 2; ++m) {
      xa[m][0] = *reinterpret_cast<const float4*>(xrow[m] + lg * 8);
      xa[m][1] = *reinterpret_cast<const float4*>(xrow[m] + lg * 8 + 4);
    }

#pragma unroll
    for (int ks = 0; ks < NKS; ++ks) {
      float4 xn[2][2];
      if (ks + 1 < NKS) {
#pragma unroll
        for (int m = 0; m < 2; ++m) {
          xn[m][0] = *reinterpret_cast<const float4*>(xrow[m] + (ks + 1) * 32 + lg * 8);
          xn[m][1] = *reinterpret_cast<const float4*>(xrow[m] + (ks + 1) * 32 + lg * 8 + 4);
        }
      }
      const bf16x8 a0 = cvt8(xa[0][0], xa[0][1]);
      const bf16x8 a1 = cvt8(xa[1][0], xa[1][1]);
#pragma unroll
      for (int n = 0; n < NT; ++n) {
        const bf16x8 bfr = *reinterpret_cast<const bf16x8*>(
            &lBT[(n * 16 + lr) * PBT + ks * 32 + lg * 8]);
        acc[0][n] = __builtin_amdgcn_mfma_f32_16x16x32_bf16(a0, bfr, acc[0][n], 0, 0, 0);
        acc[1][n] = __builtin_amdgcn_mfma_f32_16x16x32_bf16(a1, bfr, acc[1][n], 0, 0, 0);
      }
      if (ks + 1 < NKS) {
#pragma unroll
        for (int m = 0; m < 2; ++m) {
          xa[m][0] = xn[m][0];
          xa[m][1] = xn[m][1];
        }
      }
    }

    // epilogue: D frag col = n*16+lr, row = row0 + m*16 + lg*4 + r
#pragma unroll
    for (int m = 0; m < 2; ++m) {
#pragma unroll
      for (int r = 0; r < 4; ++r) {
        float* orow = ob + (size_t)(row0 + m * 16 + lg * 4 + r) * XROW;
#pragma unroll
        for (int n = 0; n < NT; ++n)
          orow[n * 16 + lr] = acc[m][n][r] + bv[n];
      }
    }
  }
}

extern "C" void kernel_launch(void* const* d_in, const int* in_sizes, int n_in,
                              void* d_out, int out_size, void* d_ws, size_t ws_size,
                              hipStream_t stream) {
  const float* x  = (const float*)d_in[0];
  const float* w  = (const float*)d_in[1];
  const float* b  = (const float*)d_in[2];
  float* out      = (float*)d_out;
  hipFuncSetAttribute((const void*)nlinear_slice,
                      hipFuncAttributeMaxDynamicSharedMemorySize, LDS_BYTES);
  nlinear_slice<<<NPOS * 2, 512, LDS_BYTES, stream>>>(x, w, b, out);
}